// Round 1
// baseline (140.697 us; speedup 1.0000x reference)
//
#include <hip/hip_runtime.h>

// LinkPredictor: out[e] = W2 . relu(W1s.z[src] + W1d.z[dst] + b1) + b2
// Factored: C = z @ [W1s|W1d]^T  (node-level GEMM, bf16 MFMA),
// then per-edge gather + fused add/relu/dot.

#define NN 100000   // nodes
#define NE 300000   // edges
#define KD 256      // in channels (K)
#define NO 512      // 2*HID output cols of node GEMM (A | B)

#define BM 128
#define BN 128
#define BK 32
#define LDT 40      // BK + 8 pad (ushort units) -> 2-way LDS conflict max

typedef __attribute__((ext_vector_type(8))) short short8;
typedef __attribute__((ext_vector_type(8))) unsigned short ushort8;
typedef __attribute__((ext_vector_type(4))) float f32x4;

__device__ __forceinline__ unsigned short f2bf(float f) {
  union { float f; unsigned int u; } v; v.f = f;
  unsigned int u = v.u;
  u += 0x7fffu + ((u >> 16) & 1u);   // RNE
  return (unsigned short)(u >> 16);
}
__device__ __forceinline__ float bf2f(unsigned short h) {
  union { unsigned int u; float f; } v; v.u = ((unsigned int)h) << 16;
  return v.f;
}

// ---- repack W1 (f32 [256][512]) -> Wt (bf16 [512][256], K-contiguous) ----
// Wt[j][k] = (j<256) ? W1[j][k] : W1[j-256][256+k]
__global__ void prep_w(const float* __restrict__ W1, unsigned short* __restrict__ Wt) {
  int idx = blockIdx.x * 256 + threadIdx.x;   // 512*256 = 131072 total
  int j = idx >> 8, k = idx & 255;
  float v = (j < 256) ? W1[j * 512 + k] : W1[(j - 256) * 512 + 256 + k];
  Wt[idx] = f2bf(v);
}

// ---- C[n][j] = sum_k z[n][k] * Wt[j][k]  (bf16 MFMA, f32 acc) ----
__global__ __launch_bounds__(256, 2) void gemm_zw(const float* __restrict__ z,
                                                  const unsigned short* __restrict__ Wt,
                                                  unsigned short* __restrict__ C) {
  __shared__ unsigned short As[BM][LDT];
  __shared__ unsigned short Bs[BN][LDT];
  const int t = threadIdx.x;
  const int mt = blockIdx.x >> 2;
  const int nt = blockIdx.x & 3;
  const int gm0 = mt * BM;
  const int n0 = nt * BN;
  const int wave = t >> 6, lane = t & 63;
  const int wm = wave >> 1, wn = wave & 1;       // 2x2 wave grid, 64x64 each
  const int l15 = lane & 15, l4 = lane >> 4;

  f32x4 acc[4][4];
#pragma unroll
  for (int m = 0; m < 4; ++m)
#pragma unroll
    for (int n = 0; n < 4; ++n) acc[m][n] = (f32x4)0.f;

  // staging coords: 2 threads per row, 16 k-elems each
  const int srow = t >> 1;
  const int skh = (t & 1) * 16;
  const bool arow_ok = (gm0 + srow) < NN;
  const float* zp = z + (size_t)(gm0 + srow) * KD + skh;
  const unsigned short* wp = Wt + (size_t)(n0 + srow) * KD + skh;

  for (int kk = 0; kk < KD; kk += BK) {
    // stage A: f32 -> bf16 in flight
    unsigned short tb[16];
    if (arow_ok) {
#pragma unroll
      for (int i = 0; i < 4; ++i) {
        float4 v = *(const float4*)(zp + kk + 4 * i);
        tb[4 * i + 0] = f2bf(v.x); tb[4 * i + 1] = f2bf(v.y);
        tb[4 * i + 2] = f2bf(v.z); tb[4 * i + 3] = f2bf(v.w);
      }
    } else {
#pragma unroll
      for (int i = 0; i < 16; ++i) tb[i] = 0;
    }
    *(ushort8*)&As[srow][skh]     = *(ushort8*)&tb[0];
    *(ushort8*)&As[srow][skh + 8] = *(ushort8*)&tb[8];
    // stage B: already bf16, straight copy
    *(ushort8*)&Bs[srow][skh]     = *(const ushort8*)(wp + kk);
    *(ushort8*)&Bs[srow][skh + 8] = *(const ushort8*)(wp + kk + 8);
    __syncthreads();

    short8 af[4], bf[4];
#pragma unroll
    for (int m = 0; m < 4; ++m)
      af[m] = *(const short8*)&As[wm * 64 + m * 16 + l15][l4 * 8];
#pragma unroll
    for (int n = 0; n < 4; ++n)
      bf[n] = *(const short8*)&Bs[wn * 64 + n * 16 + l15][l4 * 8];
#pragma unroll
    for (int m = 0; m < 4; ++m)
#pragma unroll
      for (int n = 0; n < 4; ++n)
        acc[m][n] = __builtin_amdgcn_mfma_f32_16x16x32_bf16(af[m], bf[n], acc[m][n], 0, 0, 0);
    __syncthreads();
  }

  // epilogue: C/D layout col = lane&15, row = (lane>>4)*4 + r  (m89-verified)
#pragma unroll
  for (int m = 0; m < 4; ++m) {
#pragma unroll
    for (int r = 0; r < 4; ++r) {
      int grow = gm0 + wm * 64 + m * 16 + l4 * 4 + r;
      if (grow < NN) {
        size_t base = (size_t)grow * NO + n0 + wn * 64 + l15;
#pragma unroll
        for (int n = 0; n < 4; ++n)
          C[base + n * 16] = f2bf(acc[m][n][r]);
      }
    }
  }
}

// ---- per-edge: out[e] = b2 + sum_i W2[i]*relu(A[s][i] + B[d][i] + b1[i]) ----
// 16 lanes per edge, 16 channels per lane (two 32B gathered bf16 loads/lane).
__global__ __launch_bounds__(256) void edge_mlp(const unsigned short* __restrict__ C,
                                                const int* __restrict__ ei,
                                                const float* __restrict__ b1,
                                                const float* __restrict__ W2,
                                                const float* __restrict__ b2,
                                                float* __restrict__ out) {
  const int t = threadIdx.x;
  const int lane = t & 63;
  const int g = lane >> 4;           // edge slot within wave (0..3)
  const int c0 = (lane & 15) * 16;   // channel base for this lane
  float b1v[16], w2v[16];
#pragma unroll
  for (int i = 0; i < 16; ++i) { b1v[i] = b1[c0 + i]; w2v[i] = W2[c0 + i]; }
  const float bias2 = b2[0];
  const int waveId = blockIdx.x * 4 + (t >> 6);
  const int nw = gridDim.x * 4;
  for (int e0 = waveId * 4; e0 < NE; e0 += nw * 4) {
    const int e = e0 + g;                 // NE % 4 == 0 -> always valid
    const int s = ei[e];
    const int d = ei[NE + e];
    const ushort8* ap = (const ushort8*)(C + (size_t)s * NO + c0);
    const ushort8* bp = (const ushort8*)(C + (size_t)d * NO + 256 + c0);
    ushort8 a0 = ap[0], a1 = ap[1];
    ushort8 v0 = bp[0], v1 = bp[1];
    float partial = 0.f;
#pragma unroll
    for (int j = 0; j < 8; ++j) {
      float h = bf2f(a0[j]) + bf2f(v0[j]) + b1v[j];
      h = fmaxf(h, 0.f);
      partial = fmaf(h, w2v[j], partial);
    }
#pragma unroll
    for (int j = 0; j < 8; ++j) {
      float h = bf2f(a1[j]) + bf2f(v1[j]) + b1v[8 + j];
      h = fmaxf(h, 0.f);
      partial = fmaf(h, w2v[8 + j], partial);
    }
    partial += __shfl_xor(partial, 8);
    partial += __shfl_xor(partial, 4);
    partial += __shfl_xor(partial, 2);
    partial += __shfl_xor(partial, 1);
    if ((lane & 15) == 0) out[e] = partial + bias2;
  }
}

extern "C" void kernel_launch(void* const* d_in, const int* in_sizes, int n_in,
                              void* d_out, int out_size, void* d_ws, size_t ws_size,
                              hipStream_t stream) {
  const float* z  = (const float*)d_in[0];
  const float* W1 = (const float*)d_in[1];
  const float* b1 = (const float*)d_in[2];
  const float* W2 = (const float*)d_in[3];
  const float* b2 = (const float*)d_in[4];
  const int*   ei = (const int*)d_in[5];
  float* out = (float*)d_out;

  unsigned short* C  = (unsigned short*)d_ws;          // 100000*512 bf16 = 102.4 MB
  unsigned short* Wt = C + (size_t)NN * NO;            // 512*256 bf16 = 256 KB

  prep_w<<<512, 256, 0, stream>>>(W1, Wt);
  const int mtiles = (NN + BM - 1) / BM;               // 782
  gemm_zw<<<mtiles * 4, 256, 0, stream>>>(z, Wt, C);
  edge_mlp<<<2048, 256, 0, stream>>>(C, ei, b1, W2, b2, out);
}